// Round 9
// baseline (15618.799 us; speedup 1.0000x reference)
//
#include <hip/hip_runtime.h>
#include <hip/hip_bf16.h>

#define TSTEPS 2048
#define NCHAIN 8
#define RDIM 1024
#define IDIM 128
#define HDIM 256
#define NB 16                    // blocks per chain
#define NTHR 512                 // 8 waves
#define NBLOCKS (NB * NCHAIN)    // 128 blocks: always co-resident
#define RINGD 4                  // ring depth (causally safe at 2; 4 = slack)

typedef unsigned long long u64_t;

// Agent(device)-scope RELAXED atomics: served at the device-coherent point,
// no cache-maintenance ops (R6 lesson), no fences needed at all in R9's
// protocol because value+epoch travel in ONE atomic u64.
__device__ __forceinline__ u64_t aload64(const u64_t* p) {
  return __hip_atomic_load(p, __ATOMIC_RELAXED, __HIP_MEMORY_SCOPE_AGENT);
}
__device__ __forceinline__ void astore64(u64_t* p, u64_t v) {
  __hip_atomic_store(p, v, __ATOMIC_RELAXED, __HIP_MEMORY_SCOPE_AGENT);
}
__device__ __forceinline__ u64_t pack_fe(float f, unsigned e) {
  union { float f; unsigned u; } c; c.f = f;
  return ((u64_t)e << 32) | (u64_t)c.u;
}
__device__ __forceinline__ float unpack_f(u64_t v) {
  union { unsigned u; float f; } c; c.u = (unsigned)(v & 0xffffffffu);
  return c.f;
}

__device__ __forceinline__ float wave_sum(float v) {
  v += __shfl_xor(v, 1);
  v += __shfl_xor(v, 2);
  v += __shfl_xor(v, 4);
  v += __shfl_xor(v, 8);
  v += __shfl_xor(v, 16);
  v += __shfl_xor(v, 32);
  return v;
}

// Epoch-tagged dataflow, NO global barrier. Skewed pipeline (validated R6-R8):
//   A: x_s     = tanh(w_in u_s + W x_{s-1})   (s in [0,T))   publish tag s+1
//   B: p_{s-1} = x_{s-1} @ w_pca              (s in [1,T])   publish tag s
//   C: h_{s-2} = gate(p_{s-2}, h_{s-3})       (s in [2,T+1]) publish tag s-1
// At interval s: wave0 polls x_{s-1} (tag==s), wave1 polls p_{s-2} (tag==s-1),
// wave2 polls h_{s-3} (tag==s-2); each stages into double-buffered LDS; one
// __syncthreads; all 8 waves compute. Depth-4 ring + causal chain => no WAR.
__global__ __launch_bounds__(NTHR, 2) void esn_fused(
    const float* __restrict__ u, const float* __restrict__ w_in,
    const float* __restrict__ w, const float* __restrict__ w_bias,
    const float* __restrict__ w_pca, const float* __restrict__ wzp,
    const float* __restrict__ wzh, const float* __restrict__ bz,
    float* __restrict__ out,
    u64_t* __restrict__ xslot,   // [4][8][1024] (value|epoch)
    u64_t* __restrict__ pslot,   // [4][8][256]
    u64_t* __restrict__ hslot)   // [4][8][256]
{
  const int bid = blockIdx.x;
  const int chain = bid & 7;
  const int sub = bid >> 3;            // 0..15
  const int tid = threadIdx.x;
  const int wave = tid >> 6;           // 0..7
  const int lane = tid & 63;

  // LDS staging, transposed for conflict-free access: element i lives at
  // [(i%GRP)*64 + i/GRP]  (GRP=16 for x, 4 for p/h). Double-buffered (par).
  __shared__ float LX[2][RDIM];
  __shared__ float LP[2][HDIM];
  __shared__ float LH[2][HDIM];

  // ---- phase-A weights: 8 rows of W per wave; lane owns cols [lane*16,+16) ----
  const int rrow0 = sub * 64 + wave * 8;
  float4 WA[8][4];
  #pragma unroll
  for (int j = 0; j < 8; ++j)
    #pragma unroll
    for (int i = 0; i < 4; ++i)
      WA[j][i] = *reinterpret_cast<const float4*>(
          w + (size_t)(rrow0 + j) * RDIM + lane * 16 + i * 4);
  float2 Wi[8];
  #pragma unroll
  for (int j = 0; j < 8; ++j)
    Wi[j] = *reinterpret_cast<const float2*>(w_in + (size_t)(rrow0 + j) * IDIM + lane * 2);
  const float wb = (lane < 8) ? w_bias[rrow0 + lane] : 0.f;

  // ---- phase-B weights: 2 cols of w_pca per wave; lane owns rows [lane*16,+16) ----
  const int pcol0 = sub * 16 + wave * 2;
  float Wp[2][16];
  #pragma unroll
  for (int j = 0; j < 2; ++j)
    #pragma unroll
    for (int k = 0; k < 16; ++k)
      Wp[j][k] = w_pca[(size_t)(lane * 16 + k) * HDIM + pcol0 + j];

  // ---- phase-C weights: 2 rows of wzp/wzh per wave; lane owns cols [lane*4,+4) ----
  const int grow0 = sub * 16 + wave * 2;
  float4 Zp[2], Zh[2];
  #pragma unroll
  for (int j = 0; j < 2; ++j) {
    Zp[j] = *reinterpret_cast<const float4*>(wzp + (size_t)(grow0 + j) * HDIM + lane * 4);
    Zh[j] = *reinterpret_cast<const float4*>(wzh + (size_t)(grow0 + j) * HDIM + lane * 4);
  }
  const float bzr = (lane < 2) ? bz[grow0 + lane] : 0.f;

  for (int s = 0; s <= TSTEPS + 1; ++s) {
    const int par = s & 1;

    // ---------------- poll & stage (one wave per stream) ----------------
    if (wave == 0 && s >= 1 && s <= TSTEPS) {
      // x_{s-1}: lane owns elements [lane*16, +16); poll in halves of 8
      const u64_t* xs = xslot + ((size_t)((s - 1) & 3) * NCHAIN + chain) * RDIM + lane * 16;
      #pragma unroll
      for (int half = 0; half < 2; ++half) {
        u64_t v[8];
        unsigned it = 0;
        for (;;) {
          #pragma unroll
          for (int k = 0; k < 8; ++k) v[k] = aload64(xs + half * 8 + k);
          bool ok = true;
          #pragma unroll
          for (int k = 0; k < 8; ++k) ok &= ((unsigned)(v[k] >> 32) == (unsigned)s);
          if (__all(ok ? 1 : 0)) break;
          if (++it > (1u << 16)) break;   // watchdog: wrong > hung
        }
        #pragma unroll
        for (int k = 0; k < 8; ++k)
          LX[par][(half * 8 + k) * 64 + lane] = unpack_f(v[k]);
      }
    }
    if (wave == 1 && s >= 2 && s <= TSTEPS + 1) {
      // p_{s-2}: lane owns [lane*4, +4), expect tag s-1
      const u64_t* ps = pslot + ((size_t)((s - 2) & 3) * NCHAIN + chain) * HDIM + lane * 4;
      u64_t v[4];
      unsigned it = 0;
      for (;;) {
        #pragma unroll
        for (int k = 0; k < 4; ++k) v[k] = aload64(ps + k);
        bool ok = true;
        #pragma unroll
        for (int k = 0; k < 4; ++k) ok &= ((unsigned)(v[k] >> 32) == (unsigned)(s - 1));
        if (__all(ok ? 1 : 0)) break;
        if (++it > (1u << 16)) break;
      }
      #pragma unroll
      for (int k = 0; k < 4; ++k) LP[par][k * 64 + lane] = unpack_f(v[k]);
    }
    if (wave == 2 && s >= 3 && s <= TSTEPS + 1) {
      // h_{s-3}: expect tag s-2
      const u64_t* hs = hslot + ((size_t)((s - 3) & 3) * NCHAIN + chain) * HDIM + lane * 4;
      u64_t v[4];
      unsigned it = 0;
      for (;;) {
        #pragma unroll
        for (int k = 0; k < 4; ++k) v[k] = aload64(hs + k);
        bool ok = true;
        #pragma unroll
        for (int k = 0; k < 4; ++k) ok &= ((unsigned)(v[k] >> 32) == (unsigned)(s - 2));
        if (__all(ok ? 1 : 0)) break;
        if (++it > (1u << 16)) break;
      }
      #pragma unroll
      for (int k = 0; k < 4; ++k) LH[par][k * 64 + lane] = unpack_f(v[k]);
    }
    __syncthreads();   // LDS[par] ready; double-buffer makes 1 sync/interval safe

    // ---- shared x fragment for A and B (conflict-free: stride-1 per k) ----
    float xc[16];
    if (s >= 1 && s <= TSTEPS) {
      #pragma unroll
      for (int k = 0; k < 16; ++k) xc[k] = LX[par][k * 64 + lane];
    }

    // ---------------- phase A: x_s ----------------
    if (s < TSTEPS) {
      float acc[8];
      float2 uu = *reinterpret_cast<const float2*>(
          u + ((size_t)chain * TSTEPS + s) * IDIM + lane * 2);
      #pragma unroll
      for (int j = 0; j < 8; ++j) acc[j] = Wi[j].x * uu.x + Wi[j].y * uu.y;
      if (s > 0) {
        #pragma unroll
        for (int j = 0; j < 8; ++j) {
          float a = acc[j];
          #pragma unroll
          for (int i = 0; i < 4; ++i) {
            a += WA[j][i].x * xc[i * 4 + 0];
            a += WA[j][i].y * xc[i * 4 + 1];
            a += WA[j][i].z * xc[i * 4 + 2];
            a += WA[j][i].w * xc[i * 4 + 3];
          }
          acc[j] = a;
        }
      }
      #pragma unroll
      for (int j = 0; j < 8; ++j) acc[j] = wave_sum(acc[j]);
      float v = acc[0];
      #pragma unroll
      for (int j = 1; j < 8; ++j) v = (lane == j) ? acc[j] : v;
      if (lane < 8)
        astore64(xslot + ((size_t)(s & 3) * NCHAIN + chain) * RDIM + rrow0 + lane,
                 pack_fe(tanhf(v + wb), (unsigned)(s + 1)));
    }

    // ---------------- phase B: p_{s-1} (reuses xc) ----------------
    if (s >= 1 && s <= TSTEPS) {
      const int t = s - 1;
      float a0 = 0.f, a1 = 0.f;
      #pragma unroll
      for (int k = 0; k < 16; ++k) { a0 += Wp[0][k] * xc[k]; a1 += Wp[1][k] * xc[k]; }
      a0 = wave_sum(a0);
      a1 = wave_sum(a1);
      float v = (lane == 1) ? a1 : a0;
      if (lane < 2)
        astore64(pslot + ((size_t)(t & 3) * NCHAIN + chain) * HDIM + pcol0 + lane,
                 pack_fe(v, (unsigned)(t + 1)));
    }

    // ---------------- phase C: h_{s-2} ----------------
    if (s >= 2) {
      const int t = s - 2;
      float pc[4], hc[4];
      #pragma unroll
      for (int e = 0; e < 4; ++e) pc[e] = LP[par][e * 64 + lane];
      #pragma unroll
      for (int e = 0; e < 4; ++e) hc[e] = (t > 0) ? LH[par][e * 64 + lane] : 0.f;
      float a0 = Zp[0].x * pc[0] + Zp[0].y * pc[1] + Zp[0].z * pc[2] + Zp[0].w * pc[3]
               + Zh[0].x * hc[0] + Zh[0].y * hc[1] + Zh[0].z * hc[2] + Zh[0].w * hc[3];
      float a1 = Zp[1].x * pc[0] + Zp[1].y * pc[1] + Zp[1].z * pc[2] + Zp[1].w * pc[3]
               + Zh[1].x * hc[0] + Zh[1].y * hc[1] + Zh[1].z * hc[2] + Zh[1].w * hc[3];
      a0 = wave_sum(a0);
      a1 = wave_sum(a1);
      float v = (lane == 1) ? a1 : a0;
      if (lane < 2) {
        const int row = grow0 + lane;
        float z = 1.f / (1.f + expf(-(v + bzr)));
        float pt = LP[par][(row & 3) * 64 + (row >> 2)];
        float hp = (t > 0) ? LH[par][(row & 3) * 64 + (row >> 2)] : 0.f;
        float hnew = hp + z * (pt - hp);
        astore64(hslot + ((size_t)(t & 3) * NCHAIN + chain) * HDIM + row,
                 pack_fe(hnew, (unsigned)(t + 1)));
        out[((size_t)chain * TSTEPS + t) * HDIM + row] = hnew;  // fp32 output
      }
    }
  }
}

extern "C" void kernel_launch(void* const* d_in, const int* in_sizes, int n_in,
                              void* d_out, int out_size, void* d_ws, size_t ws_size,
                              hipStream_t stream) {
  // Size-based remap (defensive); positional fallback. All fp32.
  const float* ptrs[8] = {nullptr};
  const int want[8] = {TSTEPS * NCHAIN * IDIM,  // u      2097152
                       RDIM * IDIM,             // w_in   131072
                       RDIM * RDIM,             // w      1048576
                       RDIM,                    // w_bias 1024
                       RDIM * HDIM,             // w_pca  262144
                       HDIM * HDIM,             // wzp    65536
                       HDIM * HDIM,             // wzh    65536
                       HDIM};                   // bz     256
  if (n_in == 8) {
    int used[8] = {0};
    for (int k = 0; k < 8; ++k) {
      for (int i = 0; i < n_in; ++i) {
        if (!used[i] && in_sizes[i] == want[k]) {
          ptrs[k] = (const float*)d_in[i];
          used[i] = 1;
          break;
        }
      }
    }
  }
  bool ok = true;
  for (int k = 0; k < 8; ++k) ok = ok && (ptrs[k] != nullptr);
  if (!ok)
    for (int k = 0; k < 8; ++k) ptrs[k] = (const float*)d_in[k];

  float* out = (float*)d_out;  // reference output dtype: float32

  // workspace: epoch-tagged u64 ring buffers; re-poisoned 0xAA -> must zero
  // (epoch 0 == invalid; publish tags start at 1).
  u64_t* xslot = (u64_t*)d_ws;                        // 4*8*1024
  u64_t* pslot = xslot + (size_t)RINGD * NCHAIN * RDIM; // 4*8*256
  u64_t* hslot = pslot + (size_t)RINGD * NCHAIN * HDIM; // 4*8*256
  size_t total_u64 = (size_t)RINGD * NCHAIN * (RDIM + 2 * HDIM);
  if (ws_size < total_u64 * 8) return;  // zero-output diagnostic signature
  hipMemsetAsync(d_ws, 0, total_u64 * 8, stream);

  esn_fused<<<dim3(NBLOCKS), dim3(NTHR), 0, stream>>>(
      ptrs[0], ptrs[1], ptrs[2], ptrs[3], ptrs[4], ptrs[5], ptrs[6], ptrs[7],
      out, xslot, pslot, hslot);
}

// Round 11
// 10983.366 us; speedup vs baseline: 1.4220x; 1.4220x over previous
//
#include <hip/hip_runtime.h>
#include <hip/hip_bf16.h>

#define TSTEPS 2048
#define NCHAIN 8
#define RDIM 1024
#define IDIM 128
#define HDIM 256
#define NB 16                    // blocks per chain
#define NTHR 512                 // 8 waves
#define NBLOCKS (NB * NCHAIN)    // 128 blocks: 1/CU, co-resident

typedef unsigned long long u64_t;

// Pin a float in a VGPR: value becomes an opaque asm output, so the compiler
// cannot rematerialize its defining load inside the loop (which the gbar
// "memory" clobber otherwise invites). This is what forces W residency.
#define PIN(x) asm volatile("" : "+v"(x))

// Agent(device)-scope RELAXED atomics: sc-flagged, served at the device
// coherence point. NOTE (R10 lesson): sc0 alone is SHADER-ENGINE scope (8
// CUs) -- agent scope (sc1) is the minimum for cross-block communication.
__device__ __forceinline__ float aload(const float* p) {
  return __hip_atomic_load(p, __ATOMIC_RELAXED, __HIP_MEMORY_SCOPE_AGENT);
}
__device__ __forceinline__ void astore(float* p, float v) {
  __hip_atomic_store(p, v, __ATOMIC_RELAXED, __HIP_MEMORY_SCOPE_AGENT);
}
__device__ __forceinline__ float2 aload2(const float* p) {
  u64_t q = __hip_atomic_load(reinterpret_cast<const u64_t*>(p),
                              __ATOMIC_RELAXED, __HIP_MEMORY_SCOPE_AGENT);
  union { u64_t u; float2 f; } c; c.u = q;
  return c.f;
}

__device__ __forceinline__ float wave_sum(float v) {
  v += __shfl_xor(v, 1);
  v += __shfl_xor(v, 2);
  v += __shfl_xor(v, 4);
  v += __shfl_xor(v, 8);
  v += __shfl_xor(v, 16);
  v += __shfl_xor(v, 32);
  return v;
}

// Monotonic per-chain barrier (16 arrivals/call), fence-free (R7-validated):
// per-wave vmcnt drain + __syncthreads, relaxed RMW arrival, relaxed spin.
__device__ __forceinline__ void gbar(unsigned* cnt, unsigned target) {
  asm volatile("s_waitcnt vmcnt(0) lgkmcnt(0)" ::: "memory");
  __syncthreads();
  if (threadIdx.x == 0) {
    __hip_atomic_fetch_add(cnt, 1u, __ATOMIC_RELAXED, __HIP_MEMORY_SCOPE_AGENT);
    unsigned it = 0;
    while (__hip_atomic_load(cnt, __ATOMIC_RELAXED, __HIP_MEMORY_SCOPE_AGENT) < target) {
      __builtin_amdgcn_s_sleep(1);
      if (++it > (1u << 15)) break;   // watchdog: wrong > hung
    }
  }
  __syncthreads();
}

// Skewed pipeline, ONE barrier per interval s (validated R6-R8):
//   A: x_s = tanh(w_in u_s + W x_{s-1});  B: p_{s-1} = x_{s-1} @ w_pca;
//   C: h_{s-2} = gate(p_{s-2}, h_{s-3}).  Parity-2 rings.
// __launch_bounds__(512,1): 256-VGPR budget so the ~240 pinned weight
// registers stay resident (R7-R9 ran at 128 VGPRs -> W re-read every step).
__global__ __launch_bounds__(NTHR, 1) void esn_fused(
    const float* __restrict__ u, const float* __restrict__ w_in,
    const float* __restrict__ w, const float* __restrict__ w_bias,
    const float* __restrict__ w_pca, const float* __restrict__ wzp,
    const float* __restrict__ wzh, const float* __restrict__ bz,
    float* __restrict__ out,
    float* __restrict__ x_buf,   // [2][8][1024]
    float* __restrict__ p_buf,   // [2][8][256]
    float* __restrict__ h_buf,   // [2][8][256]
    unsigned* __restrict__ barr) // [8][64] padded counters
{
  const int bid = blockIdx.x;
  const int chain = bid & 7;
  const int sub = bid >> 3;            // 0..15
  const int tid = threadIdx.x;
  const int wave = tid >> 6;           // 0..7
  const int lane = tid & 63;
  unsigned* cnt = barr + chain * 64;

  // ---- phase-A weights: 8 rows of W per wave; lane owns cols [lane*16,+16) ----
  const int rrow0 = sub * 64 + wave * 8;
  float4 WA[8][4];
  #pragma unroll
  for (int j = 0; j < 8; ++j)
    #pragma unroll
    for (int i = 0; i < 4; ++i)
      WA[j][i] = *reinterpret_cast<const float4*>(
          w + (size_t)(rrow0 + j) * RDIM + lane * 16 + i * 4);
  float2 Wi[8];
  #pragma unroll
  for (int j = 0; j < 8; ++j)
    Wi[j] = *reinterpret_cast<const float2*>(w_in + (size_t)(rrow0 + j) * IDIM + lane * 2);
  float wb = (lane < 8) ? w_bias[rrow0 + lane] : 0.f;

  // ---- phase-B weights: 2 cols of w_pca per wave ----
  const int pcol0 = sub * 16 + wave * 2;
  float Wp[2][16];
  #pragma unroll
  for (int j = 0; j < 2; ++j)
    #pragma unroll
    for (int k = 0; k < 16; ++k)
      Wp[j][k] = w_pca[(size_t)(lane * 16 + k) * HDIM + pcol0 + j];

  // ---- phase-C weights: 2 rows of wzp/wzh per wave ----
  const int grow0 = sub * 16 + wave * 2;
  float4 Zp[2], Zh[2];
  #pragma unroll
  for (int j = 0; j < 2; ++j) {
    Zp[j] = *reinterpret_cast<const float4*>(wzp + (size_t)(grow0 + j) * HDIM + lane * 4);
    Zh[j] = *reinterpret_cast<const float4*>(wzh + (size_t)(grow0 + j) * HDIM + lane * 4);
  }
  float bzr = (lane < 2) ? bz[grow0 + lane] : 0.f;

  // ---- pin all weights into live VGPRs (defeat rematerialization) ----
  #pragma unroll
  for (int j = 0; j < 8; ++j)
    #pragma unroll
    for (int i = 0; i < 4; ++i) {
      PIN(WA[j][i].x); PIN(WA[j][i].y); PIN(WA[j][i].z); PIN(WA[j][i].w);
    }
  #pragma unroll
  for (int j = 0; j < 8; ++j) { PIN(Wi[j].x); PIN(Wi[j].y); }
  #pragma unroll
  for (int j = 0; j < 2; ++j)
    #pragma unroll
    for (int k = 0; k < 16; ++k) PIN(Wp[j][k]);
  #pragma unroll
  for (int j = 0; j < 2; ++j) {
    PIN(Zp[j].x); PIN(Zp[j].y); PIN(Zp[j].z); PIN(Zp[j].w);
    PIN(Zh[j].x); PIN(Zh[j].y); PIN(Zh[j].z); PIN(Zh[j].w);
  }
  PIN(wb); PIN(bzr);

  for (int s = 0; s < TSTEPS + 2; ++s) {
    // ---- shared load: x_{s-1}, used by BOTH phase A and phase B ----
    float xc[16];
    const bool xc_valid = (s >= 1 && s <= TSTEPS);
    if (xc_valid) {
      const float* xp = x_buf + ((((s - 1) & 1) * NCHAIN) + chain) * RDIM + lane * 16;
      #pragma unroll
      for (int k = 0; k < 8; ++k) {
        float2 f = aload2(xp + 2 * k);
        xc[2 * k] = f.x;
        xc[2 * k + 1] = f.y;
      }
    }

    // ---------------- phase A: x_s ----------------
    if (s < TSTEPS) {
      float acc[8];
      float2 uu = *reinterpret_cast<const float2*>(
          u + ((size_t)chain * TSTEPS + s) * IDIM + lane * 2);
      #pragma unroll
      for (int j = 0; j < 8; ++j) acc[j] = Wi[j].x * uu.x + Wi[j].y * uu.y;
      if (s > 0) {
        #pragma unroll
        for (int j = 0; j < 8; ++j) {
          float a = acc[j];
          #pragma unroll
          for (int i = 0; i < 4; ++i) {
            a += WA[j][i].x * xc[i * 4 + 0];
            a += WA[j][i].y * xc[i * 4 + 1];
            a += WA[j][i].z * xc[i * 4 + 2];
            a += WA[j][i].w * xc[i * 4 + 3];
          }
          acc[j] = a;
        }
      }
      #pragma unroll
      for (int j = 0; j < 8; ++j) acc[j] = wave_sum(acc[j]);
      float v = acc[0];
      #pragma unroll
      for (int j = 1; j < 8; ++j) v = (lane == j) ? acc[j] : v;
      if (lane < 8)
        astore(x_buf + (((s & 1) * NCHAIN) + chain) * RDIM + rrow0 + lane,
               tanhf(v + wb));
    }

    // ---------------- phase B: p_{s-1} (reuses xc) ----------------
    if (xc_valid) {
      const int t = s - 1;
      float a0 = 0.f, a1 = 0.f;
      #pragma unroll
      for (int k = 0; k < 16; ++k) { a0 += Wp[0][k] * xc[k]; a1 += Wp[1][k] * xc[k]; }
      a0 = wave_sum(a0);
      a1 = wave_sum(a1);
      float v = (lane == 1) ? a1 : a0;
      if (lane < 2)
        astore(p_buf + (((t & 1) * NCHAIN) + chain) * HDIM + pcol0 + lane, v);
    }

    // ---------------- phase C: h_{s-2} ----------------
    if (s >= 2) {
      const int t = s - 2;
      const float* pv = p_buf + (((t & 1) * NCHAIN) + chain) * HDIM;
      const float* hv = h_buf + ((((t - 1) & 1) * NCHAIN) + chain) * HDIM;
      float pc[4], hc[4];
      {
        float2 f0 = aload2(pv + lane * 4), f1 = aload2(pv + lane * 4 + 2);
        pc[0] = f0.x; pc[1] = f0.y; pc[2] = f1.x; pc[3] = f1.y;
      }
      if (t > 0) {
        float2 f0 = aload2(hv + lane * 4), f1 = aload2(hv + lane * 4 + 2);
        hc[0] = f0.x; hc[1] = f0.y; hc[2] = f1.x; hc[3] = f1.y;
      } else {
        hc[0] = hc[1] = hc[2] = hc[3] = 0.f;
      }
      float a0 = Zp[0].x * pc[0] + Zp[0].y * pc[1] + Zp[0].z * pc[2] + Zp[0].w * pc[3]
               + Zh[0].x * hc[0] + Zh[0].y * hc[1] + Zh[0].z * hc[2] + Zh[0].w * hc[3];
      float a1 = Zp[1].x * pc[0] + Zp[1].y * pc[1] + Zp[1].z * pc[2] + Zp[1].w * pc[3]
               + Zh[1].x * hc[0] + Zh[1].y * hc[1] + Zh[1].z * hc[2] + Zh[1].w * hc[3];
      a0 = wave_sum(a0);
      a1 = wave_sum(a1);
      float v = (lane == 1) ? a1 : a0;
      if (lane < 2) {
        const int row = grow0 + lane;
        float z = 1.f / (1.f + expf(-(v + bzr)));
        float pt = aload(pv + row);
        float hp = (t > 0) ? aload(hv + row) : 0.f;
        float hnew = hp + z * (pt - hp);
        astore(h_buf + (((t & 1) * NCHAIN) + chain) * HDIM + row, hnew);
        out[((size_t)chain * TSTEPS + t) * HDIM + row] = hnew;  // fp32 output
      }
    }

    if (s <= TSTEPS) gbar(cnt, (unsigned)(s + 1) * NB);
  }
}

extern "C" void kernel_launch(void* const* d_in, const int* in_sizes, int n_in,
                              void* d_out, int out_size, void* d_ws, size_t ws_size,
                              hipStream_t stream) {
  // Size-based remap (defensive); positional fallback. All fp32.
  const float* ptrs[8] = {nullptr};
  const int want[8] = {TSTEPS * NCHAIN * IDIM, RDIM * IDIM, RDIM * RDIM, RDIM,
                       RDIM * HDIM, HDIM * HDIM, HDIM * HDIM, HDIM};
  if (n_in == 8) {
    int used[8] = {0};
    for (int k = 0; k < 8; ++k)
      for (int i = 0; i < n_in; ++i)
        if (!used[i] && in_sizes[i] == want[k]) {
          ptrs[k] = (const float*)d_in[i]; used[i] = 1; break;
        }
  }
  bool ok = true;
  for (int k = 0; k < 8; ++k) ok = ok && (ptrs[k] != nullptr);
  if (!ok)
    for (int k = 0; k < 8; ++k) ptrs[k] = (const float*)d_in[k];

  float* out = (float*)d_out;  // reference output dtype: float32

  // workspace layout (re-poisoned 0xAA before every launch -> must zero)
  float* x_buf = (float*)d_ws;                              // 2*8*1024
  float* p_buf = x_buf + 2 * NCHAIN * RDIM;                 // 2*8*256
  float* h_buf = p_buf + 2 * NCHAIN * HDIM;                 // 2*8*256
  unsigned* barr = (unsigned*)(h_buf + 2 * NCHAIN * HDIM);  // 8*64
  size_t zero_floats =
      (size_t)(2 * NCHAIN * RDIM + 2 * NCHAIN * HDIM * 2 + NCHAIN * 64);
  if (ws_size < zero_floats * 4) return;  // zero-output diagnostic signature
  hipMemsetAsync(d_ws, 0, zero_floats * 4, stream);

  esn_fused<<<dim3(NBLOCKS), dim3(NTHR), 0, stream>>>(
      ptrs[0], ptrs[1], ptrs[2], ptrs[3], ptrs[4], ptrs[5], ptrs[6], ptrs[7],
      out, x_buf, p_buf, h_buf, barr);
}